// Round 9
// baseline (340.039 us; speedup 1.0000x reference)
//
#include <hip/hip_runtime.h>
#include <stdint.h>

#define B_ 4
#define S_ 2048
#define D_ 512
#define H_ 8
#define FFN_ 2048
#define M_ (B_*S_)

typedef unsigned short u16;
typedef __attribute__((ext_vector_type(8))) __bf16 bf16x8;
typedef __attribute__((ext_vector_type(8))) u16 u16x8;
typedef __attribute__((ext_vector_type(4))) u16 u16x4;
typedef __attribute__((ext_vector_type(4))) float f32x4;

__device__ __forceinline__ u16 f2bf(float f) {
  uint32_t u = __builtin_bit_cast(uint32_t, f);
  u += 0x7FFFu + ((u >> 16) & 1u);
  return (u16)(u >> 16);
}
__device__ __forceinline__ bf16x8 ldfrag(const u16* p) {
  return __builtin_bit_cast(bf16x8, *(const u16x8*)p);
}
__device__ __forceinline__ void gld16(const void* g, void* l) {
  __builtin_amdgcn_global_load_lds(
      (const __attribute__((address_space(1))) void*)g,
      (__attribute__((address_space(3))) void*)l, 16, 0, 0);
}
// raw barrier with partial vmcnt wait (GEMM K-loop only): keeps prefetch
// loads in flight across the barrier. Safe: ds_reads are consumed before
// any wave reaches the barrier (compiler lgkmcnt waits precede the MFMAs).
template <int N>
__device__ __forceinline__ void wait_vm_barrier() {
  if constexpr (N == 0)      asm volatile("s_waitcnt vmcnt(0)\n\ts_barrier" ::: "memory");
  else if constexpr (N == 3) asm volatile("s_waitcnt vmcnt(3)\n\ts_barrier" ::: "memory");
  else if constexpr (N == 4) asm volatile("s_waitcnt vmcnt(4)\n\ts_barrier" ::: "memory");
  else if constexpr (N == 6) asm volatile("s_waitcnt vmcnt(6)\n\ts_barrier" ::: "memory");
  else if constexpr (N == 8) asm volatile("s_waitcnt vmcnt(8)\n\ts_barrier" ::: "memory");
}

// ---------------- merged weight prep: all transposes + bias concat --------
__global__ __launch_bounds__(256)
void prep(const float* __restrict__ wq, const float* __restrict__ wk,
          const float* __restrict__ wv, const float* __restrict__ w1,
          const float* __restrict__ w2, const float* __restrict__ bq,
          const float* __restrict__ bk, const float* __restrict__ bv,
          u16* __restrict__ wqkvt, u16* __restrict__ w1t,
          u16* __restrict__ w2t, float* __restrict__ bqkv) {
  int id = blockIdx.x, tid = threadIdx.x;
  if (id >= 2816) {
    int i = (id - 2816) * 256 + tid;
    bqkv[i] = i < 512 ? bq[i] : (i < 1024 ? bk[i - 512] : bv[i - 1024]);
    return;
  }
  __shared__ float t[32][33];
  const float* W; u16* dst; int K, N, bx, by;
  if (id < 768) {
    int z = id >> 8, r = id & 255;
    W = z == 0 ? wq : (z == 1 ? wk : wv);
    dst = wqkvt + (size_t)z * 512 * 512; K = 512; N = 512;
    bx = r & 15; by = r >> 4;
  } else if (id < 1792) {
    int r = id - 768; W = w1; dst = w1t; K = 512; N = 2048;
    bx = r & 63; by = r >> 6;
  } else {
    int r = id - 1792; W = w2; dst = w2t; K = 2048; N = 512;
    bx = r & 15; by = r >> 4;
  }
  int n0 = bx * 32, k0 = by * 32, x = tid & 31, y = tid >> 5;
#pragma unroll
  for (int r = 0; r < 4; r++) t[y + 8*r][x] = W[(size_t)(k0 + y + 8*r) * N + n0 + x];
  __syncthreads();
#pragma unroll
  for (int r = 0; r < 4; r++) dst[(size_t)(n0 + y + 8*r) * K + k0 + x] = f2bf(t[x][y + 8*r]);
}

// ---------------- layernorm over rows of 512 ------------------------------
template <bool OUT32, bool OUT16, bool SUM2>
__global__ __launch_bounds__(128)
void ln_k(const float* __restrict__ x, const float* __restrict__ g,
          const float* __restrict__ bta, float* __restrict__ y32,
          u16* __restrict__ y16, const u16* __restrict__ x2) {
  int row = blockIdx.x;
  int t = threadIdx.x;
  const float* xr = x + (size_t)row * 512;
  f32x4 v = *(const f32x4*)(xr + t * 4);
  if constexpr (SUM2) {
    u16x4 p2 = *(const u16x4*)(x2 + (size_t)row * 512 + t * 4);
#pragma unroll
    for (int j = 0; j < 4; j++)
      v[j] += __builtin_bit_cast(float, (uint32_t)p2[j] << 16);
  }
  float s = v.x + v.y + v.z + v.w;
  float s2 = v.x*v.x + v.y*v.y + v.z*v.z + v.w*v.w;
#pragma unroll
  for (int m = 32; m; m >>= 1) { s += __shfl_xor(s, m); s2 += __shfl_xor(s2, m); }
  __shared__ float p[4];
  int wv = t >> 6;
  if ((t & 63) == 0) { p[wv] = s; p[2 + wv] = s2; }
  __syncthreads();
  s = p[0] + p[1]; s2 = p[2] + p[3];
  float mean = s * (1.f / 512.f);
  float var = s2 * (1.f / 512.f) - mean * mean;
  float rs = rsqrtf(var + 1e-5f);
#pragma unroll
  for (int j = 0; j < 4; j++) {
    float o = (v[j] - mean) * rs * g[t*4 + j] + bta[t*4 + j];
    if constexpr (OUT32) y32[(size_t)row * 512 + t*4 + j] = o;
    if constexpr (OUT16) y16[(size_t)row * 512 + t*4 + j] = f2bf(o);
  }
}

// ---------------- GEMM: C[M,N] = A[M,K](bf16) @ Wt[N,K]^T + bias ----------
// 3-buffer LDS pipeline, ONE raw barrier per K-iter with vmcnt(L) (not 0).
// LDS swizzle: granule c of row r stored at c ^ ((r>>1)&3).
// 1-D grid, XCD-aware raster keeps each A row-stripe in one XCD's L2.
template <int NTW, int NCOL, int KSPLIT, bool RESID, bool OUT32, bool OUT16>
__global__ __launch_bounds__(256)
void gemm_db(const u16* __restrict__ A, const u16* __restrict__ Bt,
             const float* __restrict__ bias, int K, int N,
             const float* __restrict__ resid, float* __restrict__ C32,
             u16* __restrict__ C16) {
  __shared__ __align__(16) u16 As[3][128 * 32];
  __shared__ __align__(16) u16 Bs[3][NTW * 1024];
  const int tid = threadIdx.x;
  const int wave = tid >> 6, lane = tid & 63;
  const int l15 = lane & 15, quad = lane >> 4;
  const int wm = wave >> 1, wn = wave & 1;

  int lin = blockIdx.x;
  int kh = 0;
  if constexpr (KSPLIT == 2) {
    const int nblk = (M_ / 128) * NCOL;
    kh = lin >= nblk;
    lin -= kh * nblk;
  }
  const int rpx = (M_ / 128) / 8;              // row tiles per XCD
  const int xcd = lin & 7, local = lin >> 3;
  const int row0 = (xcd * rpx + local / NCOL) * 128;
  const int col0 = (local % NCOL) * (NTW * 32);
  const int klen = K / KSPLIT;
  const int kstart = kh * klen;

  f32x4 acc[4][NTW];
#pragma unroll
  for (int i = 0; i < 4; i++)
#pragma unroll
    for (int j = 0; j < NTW; j++) acc[i][j] = (f32x4){0.f, 0.f, 0.f, 0.f};

  const int lr = lane >> 2;
  const int lc = ((lane & 3) ^ ((lane >> 3) & 3)) * 8;  // swizzled source granule
  const u16* aG0 = A + (size_t)(row0 + (wave * 2) * 16 + lr) * K + lc;
  const u16* aG1 = A + (size_t)(row0 + (wave * 2 + 1) * 16 + lr) * K + lc;
  const int aO0 = (wave * 2) * 512 + lane * 8;
  const int aO1 = (wave * 2 + 1) * 512 + lane * 8;
  const u16* bG[NTW / 2];
  int bO[NTW / 2];
#pragma unroll
  for (int i = 0; i < NTW / 2; i++) {
    int ch = wave * (NTW / 2) + i;
    bG[i] = Bt + (size_t)(col0 + ch * 16 + lr) * K + lc;
    bO[i] = ch * 512 + lane * 8;
  }
  const int rsw = (l15 >> 1) & 3;  // frag-read swizzle term
  constexpr int L = 2 + NTW / 2;   // vmem loads per iter per lane

  auto issue = [&](int kof, int buf) {
    gld16(aG0 + kof, &As[buf][aO0]);
    gld16(aG1 + kof, &As[buf][aO1]);
#pragma unroll
    for (int i = 0; i < NTW / 2; i++) gld16(bG[i] + kof, &Bs[buf][bO[i]]);
  };

  const int nIter = klen >> 5;
  issue(kstart, 0);
  issue(kstart + 32, 1);  // nIter >= 16 always

  int cur = 0;
  for (int it = 0; it < nIter; it++) {
    if (it + 1 < nIter) wait_vm_barrier<L>();   // drains iter-it loads only
    else wait_vm_barrier<0>();
    int pf = cur + 2; if (pf >= 3) pf -= 3;
    if (it + 2 < nIter) issue(kstart + ((it + 2) << 5), pf);
    bf16x8 af[4], bf[NTW];
#pragma unroll
    for (int mt = 0; mt < 4; mt++)
      af[mt] = ldfrag(&As[cur][(wm * 64 + mt * 16 + l15) * 32 + ((quad ^ rsw) * 8)]);
#pragma unroll
    for (int nt = 0; nt < NTW; nt++)
      bf[nt] = ldfrag(&Bs[cur][(wn * (NTW * 16) + nt * 16 + l15) * 32 + ((quad ^ rsw) * 8)]);
#pragma unroll
    for (int mt = 0; mt < 4; mt++)
#pragma unroll
      for (int nt = 0; nt < NTW; nt++)
        acc[mt][nt] = __builtin_amdgcn_mfma_f32_16x16x32_bf16(af[mt], bf[nt], acc[mt][nt], 0, 0, 0);
    cur = cur == 2 ? 0 : cur + 1;
  }
#pragma unroll
  for (int mt = 0; mt < 4; mt++)
#pragma unroll
    for (int nt = 0; nt < NTW; nt++) {
      int n = col0 + wn * (NTW * 16) + nt * 16 + l15;
      float bv;
      if constexpr (KSPLIT == 2) bv = (kh == 0) ? bias[n] : 0.f;
      else bv = bias[n];
#pragma unroll
      for (int r = 0; r < 4; r++) {
        int m = row0 + wm * 64 + mt * 16 + quad * 4 + r;
        float val = acc[mt][nt][r] + bv;
        if constexpr (KSPLIT == 2) {
          if (kh == 0) C32[(size_t)m * N + n] = val + resid[(size_t)m * N + n];
          else C16[(size_t)m * N + n] = f2bf(val);
        } else {
          if constexpr (RESID) val += resid[(size_t)m * N + n];
          if constexpr (OUT32) C32[(size_t)m * N + n] = val;
          if constexpr (OUT16) C16[(size_t)m * N + n] = f2bf(val);
        }
      }
    }
}

// ---------------- transpose V head-wise: vt[b,h,d,s] ----------------------
__global__ __launch_bounds__(256)
void vtrans(const u16* __restrict__ qkv, u16* __restrict__ vt) {
  __shared__ u16 t[64][65];
  int s0 = blockIdx.x * 64, h = blockIdx.y, b = blockIdx.z;
  int x = threadIdx.x, y = threadIdx.y;  // (64,4)
  const u16* src = qkv + (size_t)(b * 2048 + s0) * 1536 + 1024 + h * 64;
#pragma unroll
  for (int r = 0; r < 16; r++) { int s = y + 4*r; t[s][x] = src[(size_t)s * 1536 + x]; }
  __syncthreads();
  u16* dst = vt + (size_t)((b * 8 + h) * 64) * 2048 + s0;
#pragma unroll
  for (int r = 0; r < 16; r++) { int d = y + 4*r; dst[(size_t)d * 2048 + x] = t[x][d]; }
}

// ---------------- attention: BARRIER-FREE, block = (b, h, 64 q-rows) ------
// 1024 blocks 1-D, XCD-pinned. Every MFMA operand is loaded global->VGPR
// directly in its native fragment layout (Q rows = A-frag; K rows = B-frag;
// V^T rows = B-frag). Only P round-trips through a WAVE-PRIVATE LDS slice
// (16 x PSTR, stride-17-granule -> conflict-free b128 reads). Zero
// __syncthreads: waves are fully independent; K/V 4x-redundant reads hit
// the XCD-pinned L2. vf frags pipelined one ki ahead. den via MFMA vs
// all-ones frag; P packed by truncation (bias cancels in num/den ratio).
#define PSTR 136
__global__ __launch_bounds__(256, 3)
void attn_k(const u16* __restrict__ qkv, const u16* __restrict__ vt,
            const float* __restrict__ hres, float* __restrict__ attn) {
  __shared__ __align__(16) u16 Ps[4 * 16 * PSTR];

  const int lin = blockIdx.x;
  const int xcd = lin & 7, g = lin >> 3;
  const int cq = g & 31;               // 64-row q block
  const int bh = xcd * 4 + (g >> 5);   // (b,h) pinned to xcd
  const int hh = bh & 7, b = bh >> 3;
  const int c = cq >> 1;               // 128-chunk index
  const int s0 = cq * 64;
  const int tid = threadIdx.x, wave = tid >> 6, lane = tid & 63;
  const int l15 = lane & 15, quad = lane >> 4;
  const int t_lo = (c > 4) ? c - 4 : 0;
  const int t_hi = (c + 2 < 16) ? c + 2 : 16;

  u16* Pw = Ps + wave * 16 * PSTR;     // wave-private slice

  // Q A-frags: row = s0 + wave*16 + l15, k = f*32 + quad*8
  const u16* qb = qkv + (size_t)(b * 2048 + s0 + wave * 16 + l15) * 1536 + hh * 64 + quad * 8;
  bf16x8 qf0 = ldfrag(qb);
  bf16x8 qf1 = ldfrag(qb + 32);

  // K B-frag base: row = l15 (+ kt*128 + nt*16), k = f*32 + quad*8
  const u16* kb = qkv + (size_t)(b * 2048 + l15) * 1536 + 512 + hh * 64 + quad * 8;
  // V^T B-frag base: n-col = dt*16 + l15 (d), k = kt*128 + ki*32 + quad*8 (s)
  const u16* vb = vt + (size_t)((b * 8 + hh) * 64 + l15) * 2048 + quad * 8;

  const u16x8 ones16 = {0x3F80, 0x3F80, 0x3F80, 0x3F80, 0x3F80, 0x3F80, 0x3F80, 0x3F80};
  const bf16x8 onesf = __builtin_bit_cast(bf16x8, ones16);

  f32x4 accO[4];
#pragma unroll
  for (int i = 0; i < 4; i++) accO[i] = (f32x4){0.f, 0.f, 0.f, 0.f};
  f32x4 accD = (f32x4){0.f, 0.f, 0.f, 0.f};

  for (int kt = t_lo; kt < t_hi; ++kt) {
    const u16* kbt = kb + (size_t)(kt * 128) * 1536;
    const u16* vbt = vb + kt * 128;
    // issue all K-frag loads + first V-frag set
    bf16x8 kf[8][2];
#pragma unroll
    for (int nt = 0; nt < 8; nt++) {
#pragma unroll
      for (int f = 0; f < 2; f++)
        kf[nt][f] = ldfrag(kbt + (size_t)(nt * 16) * 1536 + f * 32);
    }
    bf16x8 vf[2][4];
#pragma unroll
    for (int dt = 0; dt < 4; dt++) vf[0][dt] = ldfrag(vbt + (size_t)(dt * 16) * 2048);

    // QK^T -> exp -> P (wave-private LDS)
#pragma unroll
    for (int nt = 0; nt < 8; nt++) {
      f32x4 s4 = (f32x4){0.f, 0.f, 0.f, 0.f};
      s4 = __builtin_amdgcn_mfma_f32_16x16x32_bf16(qf0, kf[nt][0], s4, 0, 0, 0);
      s4 = __builtin_amdgcn_mfma_f32_16x16x32_bf16(qf1, kf[nt][1], s4, 0, 0, 0);
#pragma unroll
      for (int r = 0; r < 4; r++) {
        float pp = exp2f(s4[r] * (1.4426950408889634f * 0.125f));  // exp(s/8)
        Pw[(quad * 4 + r) * PSTR + nt * 16 + l15] =
            (u16)(__builtin_bit_cast(uint32_t, pp) >> 16);  // truncate
      }
    }
    // PV (pf read from own slice; vf pipelined one ki ahead)
#pragma unroll
    for (int ki = 0; ki < 4; ki++) {
      bf16x8 pf = ldfrag(Pw + l15 * PSTR + ki * 32 + quad * 8);
      if (ki < 3) {
#pragma unroll
        for (int dt = 0; dt < 4; dt++)
          vf[(ki + 1) & 1][dt] = ldfrag(vbt + (size_t)(dt * 16) * 2048 + (ki + 1) * 32);
      }
      accD = __builtin_amdgcn_mfma_f32_16x16x32_bf16(pf, onesf, accD, 0, 0, 0);
#pragma unroll
      for (int dt = 0; dt < 4; dt++)
        accO[dt] = __builtin_amdgcn_mfma_f32_16x16x32_bf16(pf, vf[ki & 1][dt], accO[dt], 0, 0, 0);
    }
  }
#pragma unroll
  for (int r = 0; r < 4; r++) {
    float dinv = 1.0f / accD[r];
    int m = s0 + wave * 16 + quad * 4 + r;
#pragma unroll
    for (int dt = 0; dt < 4; dt++) {
      size_t idx = (size_t)(b * 2048 + m) * 512 + hh * 64 + dt * 16 + l15;
      attn[idx] = accO[dt][r] * dinv + hres[idx];
    }
  }
}

extern "C" void kernel_launch(void* const* d_in, const int* in_sizes, int n_in,
                              void* d_out, int out_size, void* d_ws, size_t ws_size,
                              hipStream_t stream) {
  (void)in_sizes; (void)n_in; (void)out_size; (void)ws_size;
  const float* x       = (const float*)d_in[0];
  const float* ln_in_g = (const float*)d_in[2];
  const float* ln_in_b = (const float*)d_in[3];
  const float* wq = (const float*)d_in[4];
  const float* bq = (const float*)d_in[5];
  const float* wk = (const float*)d_in[6];
  const float* bk = (const float*)d_in[7];
  const float* wv = (const float*)d_in[8];
  const float* bv = (const float*)d_in[9];
  const float* ln1_g = (const float*)d_in[10];
  const float* ln1_b = (const float*)d_in[11];
  const float* w1 = (const float*)d_in[12];
  const float* b1 = (const float*)d_in[13];
  const float* w2 = (const float*)d_in[14];
  const float* b2 = (const float*)d_in[15];
  const float* ln2_g = (const float*)d_in[16];
  const float* ln2_b = (const float*)d_in[17];

  char* ws = (char*)d_ws;
  size_t off = 0;
  auto alloc = [&](size_t bytes) {
    void* p = ws + off;
    off = (off + bytes + 255) & ~(size_t)255;
    return p;
  };
  u16*   wqkvt = (u16*)  alloc((size_t)1536 * 512 * 2);
  float* bqkv  = (float*)alloc(1536 * 4);
  u16*   w1t   = (u16*)  alloc((size_t)2048 * 512 * 2);
  u16*   w2t   = (u16*)  alloc((size_t)512 * 2048 * 2);
  float* h32   = (float*)alloc((size_t)M_ * 512 * 4);   // later reused as out2
  u16*   h16   = (u16*)  alloc((size_t)M_ * 512 * 2);   // later: FFN2 kh1 partial
  u16*   qkv16 = (u16*)  alloc((size_t)M_ * 1536 * 2);  // + vt below = ffn-mid alias
  u16*   vtb   = (u16*)  alloc((size_t)B_ * H_ * 64 * 2048 * 2);
  float* attn32= (float*)alloc((size_t)M_ * 512 * 4);
  float* out2  = h32;
  u16*   o16   = h16;
  u16*   f16b  = qkv16;  // 8192*2048*2 bytes spans qkv16+vtb exactly

  prep<<<dim3(2822), 256, 0, stream>>>(wq, wk, wv, w1, w2, bq, bk, bv,
                                       wqkvt, w1t, w2t, bqkv);

  ln_k<true, true, false><<<M_, 128, 0, stream>>>(x, ln_in_g, ln_in_b, h32, h16, nullptr);
  gemm_db<4, 12, 1, false, false, true><<<dim3(12 * 64), 256, 0, stream>>>(
      h16, wqkvt, bqkv, 512, 1536, nullptr, nullptr, qkv16);
  vtrans<<<dim3(32, 8, 4), dim3(64, 4), 0, stream>>>(qkv16, vtb);
  attn_k<<<dim3(1024), 256, 0, stream>>>(qkv16, vtb, h32, attn32);
  ln_k<false, true, false><<<M_, 128, 0, stream>>>(attn32, ln1_g, ln1_b, nullptr, o16, nullptr);
  gemm_db<2, 32, 1, false, false, true><<<dim3(32 * 64), 256, 0, stream>>>(
      o16, w1t, b1, 512, 2048, nullptr, nullptr, f16b);
  gemm_db<2, 8, 2, false, false, false><<<dim3(2 * 8 * 64), 256, 0, stream>>>(
      f16b, w2t, b2, 2048, 512, attn32, out2, h16);
  ln_k<true, false, true><<<M_, 128, 0, stream>>>(out2, ln2_g, ln2_b, (float*)d_out, nullptr, h16);
}

// Round 11
// 289.382 us; speedup vs baseline: 1.1751x; 1.1751x over previous
//
#include <hip/hip_runtime.h>
#include <stdint.h>

#define B_ 4
#define S_ 2048
#define D_ 512
#define H_ 8
#define FFN_ 2048
#define M_ (B_*S_)

typedef unsigned short u16;
typedef __attribute__((ext_vector_type(8))) __bf16 bf16x8;
typedef __attribute__((ext_vector_type(8))) u16 u16x8;
typedef __attribute__((ext_vector_type(4))) u16 u16x4;
typedef __attribute__((ext_vector_type(4))) float f32x4;

__device__ __forceinline__ u16 f2bf(float f) {
  uint32_t u = __builtin_bit_cast(uint32_t, f);
  u += 0x7FFFu + ((u >> 16) & 1u);
  return (u16)(u >> 16);
}
__device__ __forceinline__ bf16x8 ldfrag(const u16* p) {
  return __builtin_bit_cast(bf16x8, *(const u16x8*)p);
}
__device__ __forceinline__ void gld16(const void* g, void* l) {
  __builtin_amdgcn_global_load_lds(
      (const __attribute__((address_space(1))) void*)g,
      (__attribute__((address_space(3))) void*)l, 16, 0, 0);
}
// raw barrier with partial vmcnt wait (GEMM K-loop only): keeps prefetch
// loads in flight across the barrier. Safe: ds_reads are consumed before
// any wave reaches the barrier (compiler lgkmcnt waits precede the MFMAs).
template <int N>
__device__ __forceinline__ void wait_vm_barrier() {
  if constexpr (N == 0)      asm volatile("s_waitcnt vmcnt(0)\n\ts_barrier" ::: "memory");
  else if constexpr (N == 3) asm volatile("s_waitcnt vmcnt(3)\n\ts_barrier" ::: "memory");
  else if constexpr (N == 4) asm volatile("s_waitcnt vmcnt(4)\n\ts_barrier" ::: "memory");
  else if constexpr (N == 6) asm volatile("s_waitcnt vmcnt(6)\n\ts_barrier" ::: "memory");
  else if constexpr (N == 8) asm volatile("s_waitcnt vmcnt(8)\n\ts_barrier" ::: "memory");
}

// ---------------- merged weight prep: all transposes + bias concat --------
__global__ __launch_bounds__(256)
void prep(const float* __restrict__ wq, const float* __restrict__ wk,
          const float* __restrict__ wv, const float* __restrict__ w1,
          const float* __restrict__ w2, const float* __restrict__ bq,
          const float* __restrict__ bk, const float* __restrict__ bv,
          u16* __restrict__ wqkvt, u16* __restrict__ w1t,
          u16* __restrict__ w2t, float* __restrict__ bqkv) {
  int id = blockIdx.x, tid = threadIdx.x;
  if (id >= 2816) {
    int i = (id - 2816) * 256 + tid;
    bqkv[i] = i < 512 ? bq[i] : (i < 1024 ? bk[i - 512] : bv[i - 1024]);
    return;
  }
  __shared__ float t[32][33];
  const float* W; u16* dst; int K, N, bx, by;
  if (id < 768) {
    int z = id >> 8, r = id & 255;
    W = z == 0 ? wq : (z == 1 ? wk : wv);
    dst = wqkvt + (size_t)z * 512 * 512; K = 512; N = 512;
    bx = r & 15; by = r >> 4;
  } else if (id < 1792) {
    int r = id - 768; W = w1; dst = w1t; K = 512; N = 2048;
    bx = r & 63; by = r >> 6;
  } else {
    int r = id - 1792; W = w2; dst = w2t; K = 2048; N = 512;
    bx = r & 15; by = r >> 4;
  }
  int n0 = bx * 32, k0 = by * 32, x = tid & 31, y = tid >> 5;
#pragma unroll
  for (int r = 0; r < 4; r++) t[y + 8*r][x] = W[(size_t)(k0 + y + 8*r) * N + n0 + x];
  __syncthreads();
#pragma unroll
  for (int r = 0; r < 4; r++) dst[(size_t)(n0 + y + 8*r) * K + k0 + x] = f2bf(t[x][y + 8*r]);
}

// ---------------- layernorm over rows of 512 ------------------------------
// NX = number of bf16 partial arrays to add to x (split-K combine fused)
template <bool OUT32, bool OUT16, int NX>
__global__ __launch_bounds__(128)
void ln_k(const float* __restrict__ x, const float* __restrict__ g,
          const float* __restrict__ bta, float* __restrict__ y32,
          u16* __restrict__ y16, const u16* __restrict__ p1,
          const u16* __restrict__ p2, const u16* __restrict__ p3) {
  int row = blockIdx.x;
  int t = threadIdx.x;
  const float* xr = x + (size_t)row * 512;
  f32x4 v = *(const f32x4*)(xr + t * 4);
  if constexpr (NX >= 1) {
    u16x4 a = *(const u16x4*)(p1 + (size_t)row * 512 + t * 4);
#pragma unroll
    for (int j = 0; j < 4; j++) v[j] += __builtin_bit_cast(float, (uint32_t)a[j] << 16);
  }
  if constexpr (NX >= 2) {
    u16x4 a = *(const u16x4*)(p2 + (size_t)row * 512 + t * 4);
#pragma unroll
    for (int j = 0; j < 4; j++) v[j] += __builtin_bit_cast(float, (uint32_t)a[j] << 16);
  }
  if constexpr (NX >= 3) {
    u16x4 a = *(const u16x4*)(p3 + (size_t)row * 512 + t * 4);
#pragma unroll
    for (int j = 0; j < 4; j++) v[j] += __builtin_bit_cast(float, (uint32_t)a[j] << 16);
  }
  float s = v.x + v.y + v.z + v.w;
  float s2 = v.x*v.x + v.y*v.y + v.z*v.z + v.w*v.w;
#pragma unroll
  for (int m = 32; m; m >>= 1) { s += __shfl_xor(s, m); s2 += __shfl_xor(s2, m); }
  __shared__ float p[4];
  int wv = t >> 6;
  if ((t & 63) == 0) { p[wv] = s; p[2 + wv] = s2; }
  __syncthreads();
  s = p[0] + p[1]; s2 = p[2] + p[3];
  float mean = s * (1.f / 512.f);
  float var = s2 * (1.f / 512.f) - mean * mean;
  float rs = rsqrtf(var + 1e-5f);
#pragma unroll
  for (int j = 0; j < 4; j++) {
    float o = (v[j] - mean) * rs * g[t*4 + j] + bta[t*4 + j];
    if constexpr (OUT32) y32[(size_t)row * 512 + t*4 + j] = o;
    if constexpr (OUT16) y16[(size_t)row * 512 + t*4 + j] = f2bf(o);
  }
}

// ---------------- GEMM: C[M,N] = A[M,K](bf16) @ Wt[N,K]^T + bias ----------
// 3-buffer LDS pipeline, ONE raw barrier per K-iter with vmcnt(L) (not 0).
// KSPLIT=4: kh0 -> fp32 + bias + resid (in-place safe: one thread per elem);
// kh1/2/3 -> bf16 partials to C16/C16b/C16c (combined in ln_k<NX=3>).
// Partial buffers MUST NOT alias the A operand (r10 bug: kh2->vtb raced
// with A reads, f16b spans qkv16+vtb).
// LDS swizzle: granule c of row r stored at c ^ ((r>>1)&3).
// 1-D grid, XCD-aware raster keeps each A row-stripe in one XCD's L2.
template <int NTW, int NCOL, int KSPLIT, bool RESID, bool OUT32, bool OUT16>
__global__ __launch_bounds__(256)
void gemm_db(const u16* __restrict__ A, const u16* __restrict__ Bt,
             const float* __restrict__ bias, int K, int N,
             const float* resid, float* C32, u16* __restrict__ C16,
             u16* __restrict__ C16b, u16* __restrict__ C16c) {
  __shared__ __align__(16) u16 As[3][128 * 32];
  __shared__ __align__(16) u16 Bs[3][NTW * 1024];
  const int tid = threadIdx.x;
  const int wave = tid >> 6, lane = tid & 63;
  const int l15 = lane & 15, quad = lane >> 4;
  const int wm = wave >> 1, wn = wave & 1;

  int lin = blockIdx.x;
  int kh = 0;
  if constexpr (KSPLIT > 1) {
    const int nblk = (M_ / 128) * NCOL;
    kh = lin / nblk;
    lin -= kh * nblk;
  }
  const int rpx = (M_ / 128) / 8;              // row tiles per XCD
  const int xcd = lin & 7, local = lin >> 3;
  const int row0 = (xcd * rpx + local / NCOL) * 128;
  const int col0 = (local % NCOL) * (NTW * 32);
  const int klen = K / KSPLIT;
  const int kstart = kh * klen;

  f32x4 acc[4][NTW];
#pragma unroll
  for (int i = 0; i < 4; i++)
#pragma unroll
    for (int j = 0; j < NTW; j++) acc[i][j] = (f32x4){0.f, 0.f, 0.f, 0.f};

  const int lr = lane >> 2;
  const int lc = ((lane & 3) ^ ((lane >> 3) & 3)) * 8;  // swizzled source granule
  const u16* aG0 = A + (size_t)(row0 + (wave * 2) * 16 + lr) * K + lc;
  const u16* aG1 = A + (size_t)(row0 + (wave * 2 + 1) * 16 + lr) * K + lc;
  const int aO0 = (wave * 2) * 512 + lane * 8;
  const int aO1 = (wave * 2 + 1) * 512 + lane * 8;
  const u16* bG[NTW / 2];
  int bO[NTW / 2];
#pragma unroll
  for (int i = 0; i < NTW / 2; i++) {
    int ch = wave * (NTW / 2) + i;
    bG[i] = Bt + (size_t)(col0 + ch * 16 + lr) * K + lc;
    bO[i] = ch * 512 + lane * 8;
  }
  const int rsw = (l15 >> 1) & 3;  // frag-read swizzle term
  constexpr int L = 2 + NTW / 2;   // vmem loads per iter per lane

  auto issue = [&](int kof, int buf) {
    gld16(aG0 + kof, &As[buf][aO0]);
    gld16(aG1 + kof, &As[buf][aO1]);
#pragma unroll
    for (int i = 0; i < NTW / 2; i++) gld16(bG[i] + kof, &Bs[buf][bO[i]]);
  };

  const int nIter = klen >> 5;
  issue(kstart, 0);
  issue(kstart + 32, 1);  // nIter >= 16 always

  int cur = 0;
  for (int it = 0; it < nIter; it++) {
    if (it + 1 < nIter) wait_vm_barrier<L>();   // drains iter-it loads only
    else wait_vm_barrier<0>();
    int pf = cur + 2; if (pf >= 3) pf -= 3;
    if (it + 2 < nIter) issue(kstart + ((it + 2) << 5), pf);
    bf16x8 af[4], bf[NTW];
#pragma unroll
    for (int mt = 0; mt < 4; mt++)
      af[mt] = ldfrag(&As[cur][(wm * 64 + mt * 16 + l15) * 32 + ((quad ^ rsw) * 8)]);
#pragma unroll
    for (int nt = 0; nt < NTW; nt++)
      bf[nt] = ldfrag(&Bs[cur][(wn * (NTW * 16) + nt * 16 + l15) * 32 + ((quad ^ rsw) * 8)]);
#pragma unroll
    for (int mt = 0; mt < 4; mt++)
#pragma unroll
      for (int nt = 0; nt < NTW; nt++)
        acc[mt][nt] = __builtin_amdgcn_mfma_f32_16x16x32_bf16(af[mt], bf[nt], acc[mt][nt], 0, 0, 0);
    cur = cur == 2 ? 0 : cur + 1;
  }
#pragma unroll
  for (int mt = 0; mt < 4; mt++)
#pragma unroll
    for (int nt = 0; nt < NTW; nt++) {
      int n = col0 + wn * (NTW * 16) + nt * 16 + l15;
      float bv = (kh == 0) ? bias[n] : 0.f;
#pragma unroll
      for (int r = 0; r < 4; r++) {
        int m = row0 + wm * 64 + mt * 16 + quad * 4 + r;
        size_t idx = (size_t)m * N + n;
        float val = acc[mt][nt][r] + bv;
        if constexpr (KSPLIT == 4) {
          if (kh == 0)      C32[idx] = val + resid[idx];
          else if (kh == 1) C16[idx] = f2bf(val);
          else if (kh == 2) C16b[idx] = f2bf(val);
          else              C16c[idx] = f2bf(val);
        } else {
          if constexpr (RESID) val += resid[idx];
          if constexpr (OUT32) C32[idx] = val;
          if constexpr (OUT16) C16[idx] = f2bf(val);
        }
      }
    }
}

// ---------------- transpose V head-wise: vt[b,h,d,s] ----------------------
__global__ __launch_bounds__(256)
void vtrans(const u16* __restrict__ qkv, u16* __restrict__ vt) {
  __shared__ u16 t[64][65];
  int s0 = blockIdx.x * 64, h = blockIdx.y, b = blockIdx.z;
  int x = threadIdx.x, y = threadIdx.y;  // (64,4)
  const u16* src = qkv + (size_t)(b * 2048 + s0) * 1536 + 1024 + h * 64;
#pragma unroll
  for (int r = 0; r < 16; r++) { int s = y + 4*r; t[s][x] = src[(size_t)s * 1536 + x]; }
  __syncthreads();
  u16* dst = vt + (size_t)((b * 8 + h) * 64) * 2048 + s0;
#pragma unroll
  for (int r = 0; r < 16; r++) { int d = y + 4*r; dst[(size_t)d * 2048 + x] = t[x][d]; }
}

// ---------------- attention: block = (b, h, 128 q-rows) -------------------
// 512 blocks 1-D, XCD-pinned. 128 q-rows (K-frags + staging amortized over
// 2 q-groups) + softmax diet (truncation pack, den via MFMA vs all-ones;
// truncation bias cancels in num/den). __syncthreads staging (best measured
// attn structure). Ks: 128x64 (granule c of row r at c^(r&7));
// Vts: 64x128 (granule c at (c&8)|((c&7)^(d&7))); Ps: 128xPSTR; Qs aliases.
#define PSTR 136
__global__ __launch_bounds__(256)
void attn_k(const u16* __restrict__ qkv, const u16* __restrict__ vt,
            const float* __restrict__ hres, float* __restrict__ attn) {
  __shared__ __align__(16) u16 smem[8192 + 8192 + 128 * PSTR];
  u16* Ks = smem;
  u16* Vts = smem + 8192;
  u16* Ps = smem + 16384;
  u16* Qs = Ps;

  const int lin = blockIdx.x;
  const int xcd = lin & 7, g = lin >> 3;
  const int c = g & 15;                 // 128-row q chunk
  const int bh = xcd * 4 + (g >> 4);    // (b,h) pinned to xcd
  const int hh = bh & 7, b = bh >> 3;
  const int s0 = c * 128;
  const int tid = threadIdx.x, wave = tid >> 6, lane = tid & 63;
  const int l15 = lane & 15, quad = lane >> 4;
  const int t_lo = (c > 4) ? c - 4 : 0;
  const int t_hi = (c + 2 < 16) ? c + 2 : 16;
  const int l7sw = l15 & 7;

  // stage Q (128x64), swizzled
  {
    const int cg = ((lane & 7) ^ (lane >> 3)) * 8;
    const int cp = (lane & 7) * 8;
#pragma unroll
    for (int q2 = 0; q2 < 4; q2++) {
      int r = wave * 32 + q2 * 8 + (lane >> 3);
      gld16(qkv + (size_t)(b * 2048 + s0 + r) * 1536 + hh * 64 + cg, Qs + r * 64 + cp);
    }
  }
  __syncthreads();
  bf16x8 qf[2][2];
#pragma unroll
  for (int qg = 0; qg < 2; qg++)
#pragma unroll
    for (int f = 0; f < 2; f++)
      qf[qg][f] = ldfrag(Qs + (qg * 64 + wave * 16 + l15) * 64 + (((f * 4 + quad) ^ l7sw) * 8));

  const u16x8 ones16 = {0x3F80, 0x3F80, 0x3F80, 0x3F80, 0x3F80, 0x3F80, 0x3F80, 0x3F80};
  const bf16x8 onesf = __builtin_bit_cast(bf16x8, ones16);

  f32x4 accO[2][4];
#pragma unroll
  for (int qg = 0; qg < 2; qg++)
#pragma unroll
    for (int i = 0; i < 4; i++) accO[qg][i] = (f32x4){0.f, 0.f, 0.f, 0.f};
  f32x4 accD[2] = {(f32x4){0.f, 0.f, 0.f, 0.f}, (f32x4){0.f, 0.f, 0.f, 0.f}};

  for (int kt = t_lo; kt < t_hi; ++kt) {
    __syncthreads();  // prior-iter reads done before restage
    {
      const int cgk = ((lane & 7) ^ (lane >> 3)) * 8;
      const int cpk = (lane & 7) * 8;
#pragma unroll
      for (int q2 = 0; q2 < 4; q2++) {  // K tile 128 rows
        int r = wave * 32 + q2 * 8 + (lane >> 3);
        gld16(qkv + (size_t)(b * 2048 + kt * 128 + r) * 1536 + 512 + hh * 64 + cgk,
              Ks + r * 64 + cpk);
      }
      const int cpv = (lane & 15) * 8;
#pragma unroll
      for (int q2 = 0; q2 < 4; q2++) {  // Vt tile 64 rows
        int d = (wave * 4 + q2) * 4 + (lane >> 4);
        int cgv = ((lane & 8) | ((lane & 7) ^ (lane >> 4) ^ ((q2 & 1) << 2))) * 8;
        gld16(vt + (size_t)((b * 8 + hh) * 64 + d) * 2048 + kt * 128 + cgv,
              Vts + d * 128 + cpv);
      }
    }
    __syncthreads();

#pragma unroll
    for (int nt = 0; nt < 8; nt++) {
      bf16x8 kf0 = ldfrag(Ks + (nt * 16 + l15) * 64 + ((quad ^ l7sw) * 8));
      bf16x8 kf1 = ldfrag(Ks + (nt * 16 + l15) * 64 + (((4 + quad) ^ l7sw) * 8));
#pragma unroll
      for (int qg = 0; qg < 2; qg++) {
        f32x4 s4 = (f32x4){0.f, 0.f, 0.f, 0.f};
        s4 = __builtin_amdgcn_mfma_f32_16x16x32_bf16(qf[qg][0], kf0, s4, 0, 0, 0);
        s4 = __builtin_amdgcn_mfma_f32_16x16x32_bf16(qf[qg][1], kf1, s4, 0, 0, 0);
#pragma unroll
        for (int r = 0; r < 4; r++) {
          float pp = exp2f(s4[r] * (1.4426950408889634f * 0.125f));  // exp(s/8)
          Ps[(qg * 64 + wave * 16 + quad * 4 + r) * PSTR + nt * 16 + l15] =
              (u16)(__builtin_bit_cast(uint32_t, pp) >> 16);  // truncate
        }
      }
    }
    // PV — wave reads only its own P rows, no cross-wave barrier needed
#pragma unroll
    for (int ki = 0; ki < 4; ki++) {
      bf16x8 pf[2];
#pragma unroll
      for (int qg = 0; qg < 2; qg++) {
        pf[qg] = ldfrag(Ps + (qg * 64 + wave * 16 + l15) * PSTR + (ki * 4 + quad) * 8);
        accD[qg] = __builtin_amdgcn_mfma_f32_16x16x32_bf16(pf[qg], onesf, accD[qg], 0, 0, 0);
      }
#pragma unroll
      for (int dt = 0; dt < 4; dt++) {
        int gg = ki * 4 + quad;
        bf16x8 vf = ldfrag(Vts + (dt * 16 + l15) * 128 + (((gg & 8) | ((gg & 7) ^ l7sw)) * 8));
#pragma unroll
        for (int qg = 0; qg < 2; qg++)
          accO[qg][dt] = __builtin_amdgcn_mfma_f32_16x16x32_bf16(pf[qg], vf, accO[qg][dt], 0, 0, 0);
      }
    }
  }
#pragma unroll
  for (int qg = 0; qg < 2; qg++)
#pragma unroll
    for (int r = 0; r < 4; r++) {
      float dinv = 1.0f / accD[qg][r];
      int m = s0 + qg * 64 + wave * 16 + quad * 4 + r;
#pragma unroll
      for (int dt = 0; dt < 4; dt++) {
        size_t idx = (size_t)(b * 2048 + m) * 512 + hh * 64 + dt * 16 + l15;
        attn[idx] = accO[qg][dt][r] * dinv + hres[idx];
      }
    }
}

extern "C" void kernel_launch(void* const* d_in, const int* in_sizes, int n_in,
                              void* d_out, int out_size, void* d_ws, size_t ws_size,
                              hipStream_t stream) {
  (void)in_sizes; (void)n_in; (void)out_size; (void)ws_size;
  const float* x       = (const float*)d_in[0];
  const float* ln_in_g = (const float*)d_in[2];
  const float* ln_in_b = (const float*)d_in[3];
  const float* wq = (const float*)d_in[4];
  const float* bq = (const float*)d_in[5];
  const float* wk = (const float*)d_in[6];
  const float* bk = (const float*)d_in[7];
  const float* wv = (const float*)d_in[8];
  const float* bv = (const float*)d_in[9];
  const float* ln1_g = (const float*)d_in[10];
  const float* ln1_b = (const float*)d_in[11];
  const float* w1 = (const float*)d_in[12];
  const float* b1 = (const float*)d_in[13];
  const float* w2 = (const float*)d_in[14];
  const float* b2 = (const float*)d_in[15];
  const float* ln2_g = (const float*)d_in[16];
  const float* ln2_b = (const float*)d_in[17];

  char* ws = (char*)d_ws;
  size_t off = 0;
  auto alloc = [&](size_t bytes) {
    void* p = ws + off;
    off = (off + bytes + 255) & ~(size_t)255;
    return p;
  };
  u16*   wqkvt = (u16*)  alloc((size_t)1536 * 512 * 2);
  float* bqkv  = (float*)alloc(1536 * 4);
  u16*   w1t   = (u16*)  alloc((size_t)2048 * 512 * 2);
  u16*   w2t   = (u16*)  alloc((size_t)512 * 2048 * 2);
  float* h32   = (float*)alloc((size_t)M_ * 512 * 4);   // hres; later FFN2 kh2+kh3 partials
  u16*   h16   = (u16*)  alloc((size_t)M_ * 512 * 2);   // ln-in bf16 / o16 / FFN2 kh1 partial
  u16*   qkv16 = (u16*)  alloc((size_t)M_ * 1536 * 2);  // + vtb = f16b (FFN mid)
  u16*   vtb   = (u16*)  alloc((size_t)B_ * H_ * 64 * 2048 * 2);  // part of f16b span — never reused!
  float* attn32= (float*)alloc((size_t)M_ * 512 * 4);   // attn out; FFN2 kh0 in-place
  u16*   o16   = h16;
  u16*   f16b  = qkv16;  // 8192*2048*2 bytes spans qkv16+vtb exactly
  // FFN2 bf16 partials: kh1 -> h16 (free after FFN1); kh2/kh3 -> the two
  // halves of h32 (16 MB fp32 hres buffer, free after attn_k). None of
  // these alias f16b (the FFN2 A operand) — that aliasing was the r10 bug.
  u16*   p2b   = (u16*)h32;
  u16*   p3b   = (u16*)h32 + (size_t)M_ * 512;

  prep<<<dim3(2822), 256, 0, stream>>>(wq, wk, wv, w1, w2, bq, bk, bv,
                                       wqkvt, w1t, w2t, bqkv);

  ln_k<true, true, 0><<<M_, 128, 0, stream>>>(x, ln_in_g, ln_in_b, h32, h16,
                                              nullptr, nullptr, nullptr);
  gemm_db<4, 12, 1, false, false, true><<<dim3(12 * 64), 256, 0, stream>>>(
      h16, wqkvt, bqkv, 512, 1536, nullptr, nullptr, qkv16, nullptr, nullptr);
  vtrans<<<dim3(32, 8, 4), dim3(64, 4), 0, stream>>>(qkv16, vtb);
  attn_k<<<dim3(512), 256, 0, stream>>>(qkv16, vtb, h32, attn32);
  ln_k<false, true, 0><<<M_, 128, 0, stream>>>(attn32, ln1_g, ln1_b, nullptr, o16,
                                               nullptr, nullptr, nullptr);
  gemm_db<2, 32, 1, false, false, true><<<dim3(32 * 64), 256, 0, stream>>>(
      o16, w1t, b1, 512, 2048, nullptr, nullptr, f16b, nullptr, nullptr);
  gemm_db<2, 8, 4, false, false, false><<<dim3(4 * 8 * 64), 256, 0, stream>>>(
      f16b, w2t, b2, 2048, 512, attn32, attn32, h16, p2b, p3b);
  ln_k<true, false, 3><<<M_, 128, 0, stream>>>(attn32, ln2_g, ln2_b, (float*)d_out,
                                               nullptr, h16, p2b, p3b);
}